// Round 17
// baseline (116.121 us; speedup 1.0000x reference)
//
#include <hip/hip_runtime.h>
#include <hip/hip_bf16.h>
#include <math.h>

typedef __bf16 bf16_t;
typedef __attribute__((ext_vector_type(8))) __bf16 bf16x8;
typedef __attribute__((ext_vector_type(4))) float f32x4;
typedef __attribute__((ext_vector_type(16))) float f32x16;
typedef __attribute__((ext_vector_type(4))) unsigned u32x4;

#define AS1(p) ((__attribute__((address_space(1))) void*)(p))
#define AS3(p) ((__attribute__((address_space(3))) void*)(p))

__device__ inline unsigned pkbf(float a, float b) {
  bf16_t x = (bf16_t)a, y = (bf16_t)b;
  return (unsigned)__builtin_bit_cast(unsigned short, x) |
         ((unsigned)__builtin_bit_cast(unsigned short, y) << 16);
}
__device__ inline f32x16 zero16() {
  f32x16 z;
#pragma unroll
  for (int r = 0; r < 16; ++r) z[r] = 0.f;
  return z;
}

__device__ inline void cvt8(const float* __restrict__ in, bf16_t* __restrict__ out, int i) {
  const float4* p = (const float4*)in;
  float4 a = p[2 * i], b = p[2 * i + 1];
  bf16x8 o;
  o[0] = (bf16_t)a.x; o[1] = (bf16_t)a.y; o[2] = (bf16_t)a.z; o[3] = (bf16_t)a.w;
  o[4] = (bf16_t)b.x; o[5] = (bf16_t)b.y; o[6] = (bf16_t)b.z; o[7] = (bf16_t)b.w;
  ((bf16x8*)out)[i] = o;
}

// ---------------- fused prep: 3x f32->bf16 cvt + RoPE tables ----------------
__global__ __launch_bounds__(256)
void prep_all(const float* __restrict__ hid, const float* __restrict__ wqkv,
              const float* __restrict__ wo, bf16_t* __restrict__ hidb,
              bf16_t* __restrict__ wqkvb, bf16_t* __restrict__ wob,
              float* __restrict__ cosb, float* __restrict__ sinb) {
  const int bid = blockIdx.x, tid = threadIdx.x;
  if (bid < 2048) {
    cvt8(hid, hidb, bid * 256 + tid);
  } else if (bid < 3584) {
    cvt8(wqkv, wqkvb, (bid - 2048) * 256 + tid);
  } else if (bid < 4096) {
    cvt8(wo, wob, (bid - 3584) * 256 + tid);
  } else {
    int t = (bid - 4096) * 256 + tid;  // 65536 entries: [2048][32]
    int s = t >> 5, i = t & 31;
    float inv = powf(10000.0f, -(float)i / 32.0f);
    float sv, cv;
    sincosf((float)s * inv, &sv, &cv);
    cosb[t] = cv;
    sinb[t] = sv;
  }
}

// ---- BK=32 triple-buffer staging: 4 loads/stage/thread, dest linear in tid ----
#define GSTAGE32(KT, BUF)                                                                  \
  do {                                                                                     \
    const int k0_ = (KT) << 5;                                                             \
    const int ar_ = tid >> 2, ac_ = (tid & 3) * 8;                                         \
    __builtin_amdgcn_global_load_lds(AS1(A + (size_t)(m0 + ar_) * K + k0_ + ac_),          \
                                     AS3(&lA[BUF][ar_ * 32 + ac_]), 16, 0, 0);             \
    __builtin_amdgcn_global_load_lds(AS1(A + (size_t)(m0 + 64 + ar_) * K + k0_ + ac_),     \
                                     AS3(&lA[BUF][(64 + ar_) * 32 + ac_]), 16, 0, 0);      \
    __builtin_amdgcn_global_load_lds(AS1(B + (size_t)(n0 + ar_) * K + k0_ + ac_),          \
                                     AS3(&lB[BUF][ar_ * 32 + ac_]), 16, 0, 0);             \
    __builtin_amdgcn_global_load_lds(AS1(B + (size_t)(n0 + 64 + ar_) * K + k0_ + ac_),     \
                                     AS3(&lB[BUF][(64 + ar_) * 32 + ac_]), 16, 0, 0);      \
  } while (0)

// ---- single-barrier K-loop body: [wait; barrier; stage(kt+2); compute(kt)] ----
// Safety: after the barrier every wave finished compute(kt-1); stage(kt+2) writes
// buf (kt+2)%3 == (kt-1)%3 whose last reader was compute(kt-1). First re-read is
// compute(kt+2), gated by its own wait. One barrier per iteration.

// ---------------- QKV GEMM, BK=32 triple-buffer + fused rope/pack epilogue ----
__global__ __launch_bounds__(256, 3)
void gemm_qkv(const bf16_t* __restrict__ A, const bf16_t* __restrict__ B,
              bf16_t* __restrict__ qkv, bf16_t* __restrict__ Kp,
              const float* __restrict__ cosb, const float* __restrict__ sinb) {
  __shared__ __align__(16) bf16_t lA[3][128 * 32];
  __shared__ __align__(16) bf16_t lB[3][128 * 32];
  const int K = 1024;
  const int tid = threadIdx.x;
  const int wid = tid >> 6, lane = tid & 63;
  const int lr = lane & 15, lg = lane >> 4;
  const int nwg = gridDim.x * gridDim.y;
  int lin = blockIdx.y * gridDim.x + blockIdx.x;
  lin = (lin & 7) * (nwg >> 3) + (lin >> 3);
  const int m0 = (lin / gridDim.x) * 128, n0 = (lin % gridDim.x) * 128;
  const int wm = (wid >> 1) * 64, wn = (wid & 1) * 64;
  f32x4 acc[4][4];
#pragma unroll
  for (int i = 0; i < 4; ++i)
#pragma unroll
    for (int j = 0; j < 4; ++j) acc[i][j] = f32x4{0.f, 0.f, 0.f, 0.f};

  const int nk = 32;
  GSTAGE32(0, 0);
  GSTAGE32(1, 1);
  int cbuf = 0;
  for (int kt = 0; kt < nk; ++kt) {
    if (kt + 1 < nk) { asm volatile("s_waitcnt vmcnt(4)" ::: "memory"); }
    else             { asm volatile("s_waitcnt vmcnt(0)" ::: "memory"); }
    __builtin_amdgcn_s_barrier();          // stage(kt) visible; compute(kt-1) done all-waves
    if (kt + 2 < nk) {
      const int sb = cbuf == 0 ? 2 : cbuf - 1;  // (kt+2)%3 == (kt-1)%3
      GSTAGE32(kt + 2, sb);
    }
    {
      bf16x8 af[4], bfr[4];
#pragma unroll
      for (int i = 0; i < 4; ++i) {
        af[i]  = *(const bf16x8*)&lA[cbuf][(wm + i * 16 + lr) * 32 + lg * 8];
        bfr[i] = *(const bf16x8*)&lB[cbuf][(wn + i * 16 + lr) * 32 + lg * 8];
      }
#pragma unroll
      for (int i = 0; i < 4; ++i)
#pragma unroll
        for (int j = 0; j < 4; ++j)
          acc[i][j] = __builtin_amdgcn_mfma_f32_16x16x32_bf16(af[i], bfr[j], acc[i][j], 0, 0, 0);
    }
    cbuf = cbuf == 2 ? 0 : cbuf + 1;
  }
  // -------- fused epilogue --------
  const int sec = n0 >> 10;                  // 0=Q 1=K 2=V (uniform per block)
  const int hcol = ((n0 + wn) & 1023) >> 6;  // head index (uniform per wave)
  if (sec == 2) {
    // V^T: lane owns d-col (j*16+lr); 4 consecutive kv rows per acc reg.
#pragma unroll
    for (int i = 0; i < 4; ++i) {
      int token0 = m0 + wm + i * 16 + lg * 4;  // r = 0 row
      int bb = token0 >> 11;
      int t = (token0 & 2047) >> 6;
      int kv0 = token0 & 63;  // multiple of 4
      bf16_t* vd = qkv + ((size_t)(bb * 2048 + t * 64)) * 3072 + 2048 + hcol * 64;
#pragma unroll
      for (int j = 0; j < 4; ++j) {
        int d = j * 16 + lr;
        uint2 w;
        w.x = pkbf(acc[i][j][0], acc[i][j][1]);
        w.y = pkbf(acc[i][j][2], acc[i][j][3]);
        *(uint2*)(vd + (size_t)d * 3072 + (((kv0 >> 3) ^ (d & 7)) * 8) + (kv0 & 7)) = w;
      }
    }
  } else {
    const float SC = sec ? 1.0f : 0.125f * 1.4426950408889634f;  // Q: 1/8*log2e
#pragma unroll
    for (int i = 0; i < 4; ++i)
#pragma unroll
      for (int r = 0; r < 4; ++r) {
        int token = m0 + wm + i * 16 + lg * 4 + r;
        int s = token & 2047;
#pragma unroll
        for (int j = 0; j < 2; ++j) {
          int f = j * 16 + lr;  // rope pair (f, f+32) = acc regs j and j+2
          float cv = cosb[s * 32 + f], sv = sinb[s * 32 + f];
          float x1 = acc[i][j][r], x2 = acc[i][j + 2][r];
          float y1 = (x1 * cv - x2 * sv) * SC;
          float y2 = (x2 * cv + x1 * sv) * SC;
          if (sec == 0) {
            bf16_t* qd = qkv + (size_t)token * 3072 + hcol * 64;
            qd[f] = (bf16_t)y1;
            qd[f + 32] = (bf16_t)y2;
          } else {
            int bb = token >> 11, t = (token & 2047) >> 6, rk = token & 63;
            bf16_t* kd = Kp + ((size_t)((bb * 16 + hcol) * 32 + t)) * 4096 + rk * 64;
            int c1 = f >> 3;  // chunk of d=f; d+32 -> c1+4
            kd[((c1 ^ (rk & 7)) * 8) + (lr & 7)] = (bf16_t)y1;
            kd[(((c1 + 4) ^ (rk & 7)) * 8) + (lr & 7)] = (bf16_t)y2;
          }
        }
      }
  }
}

// ---------------- out-proj GEMM (f32 out), BK=32 triple-buffer, single-barrier ----
__global__ __launch_bounds__(256, 3)
void gemm_nt_f32(const bf16_t* __restrict__ A, const bf16_t* __restrict__ B,
                 float* __restrict__ C, int M, int N, int K) {
  __shared__ __align__(16) bf16_t lA[3][128 * 32];
  __shared__ __align__(16) bf16_t lB[3][128 * 32];
  const int tid = threadIdx.x;
  const int wid = tid >> 6, lane = tid & 63;
  const int lr = lane & 15, lg = lane >> 4;
  const int nwg = gridDim.x * gridDim.y;
  int lin = blockIdx.y * gridDim.x + blockIdx.x;
  lin = (lin & 7) * (nwg >> 3) + (lin >> 3);
  const int m0 = (lin / gridDim.x) * 128, n0 = (lin % gridDim.x) * 128;
  const int wm = (wid >> 1) * 64, wn = (wid & 1) * 64;
  f32x4 acc[4][4];
#pragma unroll
  for (int i = 0; i < 4; ++i)
#pragma unroll
    for (int j = 0; j < 4; ++j) acc[i][j] = f32x4{0.f, 0.f, 0.f, 0.f};

  const int nk = K >> 5;
  GSTAGE32(0, 0);
  GSTAGE32(1, 1);
  int cbuf = 0;
  for (int kt = 0; kt < nk; ++kt) {
    if (kt + 1 < nk) { asm volatile("s_waitcnt vmcnt(4)" ::: "memory"); }
    else             { asm volatile("s_waitcnt vmcnt(0)" ::: "memory"); }
    __builtin_amdgcn_s_barrier();
    if (kt + 2 < nk) {
      const int sb = cbuf == 0 ? 2 : cbuf - 1;
      GSTAGE32(kt + 2, sb);
    }
    {
      bf16x8 af[4], bfr[4];
#pragma unroll
      for (int i = 0; i < 4; ++i) {
        af[i]  = *(const bf16x8*)&lA[cbuf][(wm + i * 16 + lr) * 32 + lg * 8];
        bfr[i] = *(const bf16x8*)&lB[cbuf][(wn + i * 16 + lr) * 32 + lg * 8];
      }
#pragma unroll
      for (int i = 0; i < 4; ++i)
#pragma unroll
        for (int j = 0; j < 4; ++j)
          acc[i][j] = __builtin_amdgcn_mfma_f32_16x16x32_bf16(af[i], bfr[j], acc[i][j], 0, 0, 0);
    }
    cbuf = cbuf == 2 ? 0 : cbuf + 1;
  }
#pragma unroll
  for (int i = 0; i < 4; ++i)
#pragma unroll
    for (int j = 0; j < 4; ++j)
#pragma unroll
      for (int r = 0; r < 4; ++r) {
        int row = m0 + wm + i * 16 + lg * 4 + r;
        int col = n0 + wn + j * 16 + lr;
        C[(size_t)row * N + col] = acc[i][j][r];
      }
}

// ---------------- flash attention (round-12 best-measured): split-kv halves ----
__device__ const unsigned char ROLE_LUT[44] = {
    19, 18, 17, 16,
    15, 95, 159, 158,
    14, 94, 93, 157,
    13, 92, 156, 91, 155, 154,
    12, 90, 89, 153, 152,
    11, 88, 87, 151, 150,
    10, 86, 85, 149, 148,
    9, 84,
    8, 7, 6, 5, 4, 3, 2, 1, 0};

__global__ __launch_bounds__(128, 2)
void attn_fwd(const bf16_t* __restrict__ qkv, const bf16_t* __restrict__ Kp,
              bf16_t* __restrict__ O, bf16_t* __restrict__ Po, float* __restrict__ Plp) {
  __shared__ __align__(16) bf16_t Ksh[2][4096];
  __shared__ __align__(16) bf16_t Vsh[2][4096];
  const int tid = threadIdx.x, wid = tid >> 6, lane = tid & 63;
  const int ln = lane & 31, h = lane >> 5;
  const int lin = blockIdx.x;
  const int e = ROLE_LUT[lin >> 5];           // role, longest chains at low lin
  const int bh = lin & 31;                    // same-bh blocks share XCD (lin%8)
  const int c = e & 31, kind = e >> 6;
  const int b = bh >> 4, hd = bh & 15;
  const int t0 = (kind == 2) ? ((c + 1) >> 1) : 0;
  const int t1 = (kind == 1) ? ((c + 1) >> 1) : c + 1;
  const int qw = c * 64 + wid * 32;

  const bf16_t* Qrow = qkv + ((size_t)(b * 2048 + qw + ln)) * 3072 + hd * 64;
  bf16x8 qf[4];
#pragma unroll
  for (int t = 0; t < 4; ++t) qf[t] = *(const bf16x8*)(Qrow + t * 16 + h * 8);

  f32x16 o0 = zero16(), o1 = zero16();
  float lp = 0.f;

  const bf16_t* Kbase = Kp + ((size_t)bh * 32) * 4096 + tid * 8;
  const bf16_t* Vbase = qkv + ((size_t)(b * 2048 + (tid >> 3))) * 3072 + 2048 + hd * 64 + (tid & 7) * 8;

#define STAGE(T, BUF)                                                                     \
  do {                                                                                    \
    const bf16_t* ks = Kbase + (size_t)(T) * 4096;                                        \
    __builtin_amdgcn_global_load_lds(AS1(ks),        AS3(&Ksh[BUF][tid * 8]), 16, 0, 0);  \
    __builtin_amdgcn_global_load_lds(AS1(ks + 1024), AS3(&Ksh[BUF][1024 + tid * 8]), 16, 0, 0); \
    __builtin_amdgcn_global_load_lds(AS1(ks + 2048), AS3(&Ksh[BUF][2048 + tid * 8]), 16, 0, 0); \
    __builtin_amdgcn_global_load_lds(AS1(ks + 3072), AS3(&Ksh[BUF][3072 + tid * 8]), 16, 0, 0); \
    const bf16_t* vs = Vbase + (size_t)(T) * 64 * 3072;                                   \
    __builtin_amdgcn_global_load_lds(AS1(vs),             AS3(&Vsh[BUF][tid * 8]), 16, 0, 0);        \
    __builtin_amdgcn_global_load_lds(AS1(vs + 16 * 3072), AS3(&Vsh[BUF][1024 + tid * 8]), 16, 0, 0); \
    __builtin_amdgcn_global_load_lds(AS1(vs + 32 * 3072), AS3(&Vsh[BUF][2048 + tid * 8]), 16, 0, 0); \
    __builtin_amdgcn_global_load_lds(AS1(vs + 48 * 3072), AS3(&Vsh[BUF][3072 + tid * 8]), 16, 0, 0); \
  } while (0)

  STAGE(t0, t0 & 1);
  for (int t = t0; t < t1; ++t) {
    asm volatile("s_waitcnt vmcnt(0)" ::: "memory");  // STAGE(t) done
    __builtin_amdgcn_s_barrier();                     // all waves staged; prev buf free
    if (t + 1 < t1) STAGE(t + 1, (t + 1) & 1);        // flies under this item's compute
    const bf16_t* K = &Ksh[t & 1][0];
    const bf16_t* V = &Vsh[t & 1][0];
    f32x16 s0 = zero16(), s1 = zero16();
    __builtin_amdgcn_s_setprio(1);
#pragma unroll
    for (int u = 0; u < 4; ++u) {
      const int ch = 2 * u + h;
      bf16x8 k0 = *(const bf16x8*)&K[ln * 64 + ((ch ^ (ln & 7)) * 8)];
      bf16x8 k1 = *(const bf16x8*)&K[(32 + ln) * 64 + ((ch ^ (ln & 7)) * 8)];
      s0 = __builtin_amdgcn_mfma_f32_32x32x16_bf16(k0, qf[u], s0, 0, 0, 0);
      s1 = __builtin_amdgcn_mfma_f32_32x32x16_bf16(k1, qf[u], s1, 0, 0, 0);
    }
    __builtin_amdgcn_s_setprio(0);
    if (t == c) {  // diagonal tile
      const int qg = qw + ln, k0g = t * 64;
#pragma unroll
      for (int r = 0; r < 16; ++r) {
        int kv = k0g + (r & 3) + 8 * (r >> 2) + 4 * h;
        if (kv > qg) s0[r] = -3e38f;
        if (kv + 32 > qg) s1[r] = -3e38f;
      }
    }
#pragma unroll
    for (int r = 0; r < 16; ++r) {
      float p0 = __builtin_amdgcn_exp2f(s0[r]); lp += p0; s0[r] = p0;
      float p1 = __builtin_amdgcn_exp2f(s1[r]); lp += p1; s1[r] = p1;
    }
    __builtin_amdgcn_s_setprio(1);
#pragma unroll
    for (int u = 0; u < 4; ++u) {
      const int w = u & 1;
      f32x16 sv = (u >> 1) ? s1 : s0;
      unsigned x  = pkbf(sv[8 * w + 0], sv[8 * w + 1]);
      unsigned x2 = pkbf(sv[8 * w + 2], sv[8 * w + 3]);
      unsigned y  = pkbf(sv[8 * w + 4], sv[8 * w + 5]);
      unsigned y2 = pkbf(sv[8 * w + 6], sv[8 * w + 7]);
      asm volatile("v_permlane32_swap_b32 %0, %1" : "+v"(x), "+v"(y));
      asm volatile("v_permlane32_swap_b32 %0, %1" : "+v"(x2), "+v"(y2));
      u32x4 pw; pw[0] = x; pw[1] = x2; pw[2] = y; pw[3] = y2;
      bf16x8 pf = __builtin_bit_cast(bf16x8, pw);
      const int ch = 2 * u + h;
      bf16x8 v0 = *(const bf16x8*)&V[ln * 64 + ((ch ^ (ln & 7)) * 8)];
      bf16x8 v1 = *(const bf16x8*)&V[(32 + ln) * 64 + ((ch ^ (ln & 7)) * 8)];
      o0 = __builtin_amdgcn_mfma_f32_32x32x16_bf16(v0, pf, o0, 0, 0, 0);
      o1 = __builtin_amdgcn_mfma_f32_32x32x16_bf16(v1, pf, o1, 0, 0, 0);
    }
    __builtin_amdgcn_s_setprio(0);
  }
#undef STAGE
  float lpf = lp + __shfl_xor(lp, 32, 64);
  if (kind == 0) {
    float inv = 1.0f / lpf;
    bf16_t* Oaddr = O + ((size_t)(b * 2048 + qw + ln)) * 1024 + hd * 64;
#pragma unroll
    for (int D = 0; D < 2; ++D) {
      f32x16 ov = D ? o1 : o0;
#pragma unroll
      for (int Q = 0; Q < 4; ++Q) {
        uint2 w;
        w.x = pkbf(ov[4 * Q + 0] * inv, ov[4 * Q + 1] * inv);
        w.y = pkbf(ov[4 * Q + 2] * inv, ov[4 * Q + 3] * inv);
        *(uint2*)(Oaddr + D * 32 + Q * 8 + 4 * h) = w;
      }
    }
  } else {
    const int slot = (bh * 12 + (c - 20)) * 2 + (kind - 1);
    const int qi = wid * 32 + ln;
    if (h == 0) Plp[slot * 64 + qi] = lpf;
    bf16_t* Paddr = Po + ((size_t)(slot * 64 + qi)) * 64;
#pragma unroll
    for (int D = 0; D < 2; ++D) {
      f32x16 ov = D ? o1 : o0;
#pragma unroll
      for (int Q = 0; Q < 4; ++Q) {
        uint2 w;
        w.x = pkbf(ov[4 * Q + 0], ov[4 * Q + 1]);
        w.y = pkbf(ov[4 * Q + 2], ov[4 * Q + 3]);
        *(uint2*)(Paddr + D * 32 + Q * 8 + 4 * h) = w;
      }
    }
  }
}

// ---------------- combine split-kv partials: O = (oA+oB)/(lpA+lpB) ----
__global__ __launch_bounds__(64)
void attn_combine(const bf16_t* __restrict__ Po, const float* __restrict__ Plp,
                  bf16_t* __restrict__ O) {
  const int blk = blockIdx.x;  // 384 = bh*12 + sc
  const int bh = blk / 12, sc = blk % 12;
  const int b = bh >> 4, hd = bh & 15;
  const int c = 20 + sc;
  const int q = threadIdx.x;  // 64 q-rows
  const int slotA = (bh * 12 + sc) * 2, slotB = slotA + 1;
  float inv = 1.0f / (Plp[slotA * 64 + q] + Plp[slotB * 64 + q]);
  const bf16x8* pa = (const bf16x8*)(Po + ((size_t)(slotA * 64 + q)) * 64);
  const bf16x8* pb = (const bf16x8*)(Po + ((size_t)(slotB * 64 + q)) * 64);
  bf16_t* oaddr = O + ((size_t)(b * 2048 + c * 64 + q)) * 1024 + hd * 64;
#pragma unroll
  for (int j = 0; j < 8; ++j) {
    bf16x8 a = pa[j], v = pb[j];
    bf16x8 w;
#pragma unroll
    for (int k = 0; k < 8; ++k) w[k] = (bf16_t)(((float)a[k] + (float)v[k]) * inv);
    ((bf16x8*)oaddr)[j] = w;
  }
}

extern "C" void kernel_launch(void* const* d_in, const int* in_sizes, int n_in,
                              void* d_out, int out_size, void* d_ws, size_t ws_size,
                              hipStream_t stream) {
  const float* hid  = (const float*)d_in[0];   // [4096,1024]
  const float* wqkv = (const float*)d_in[1];   // [3072,1024]
  const float* wo   = (const float*)d_in[2];   // [1024,1024]
  float* out = (float*)d_out;                  // [4096,1024] f32
  char* ws = (char*)d_ws;
  bf16_t* hidb  = (bf16_t*)(ws);                  // 0..8M
  bf16_t* wqkvb = (bf16_t*)(ws + 8388608);        // 8M..14M
  bf16_t* wob   = (bf16_t*)(ws + 14680064);       // 14M..16M
  bf16_t* qkvb  = (bf16_t*)(ws + 16777216);       // 16M..40M (Q | dead | V^T)
  float*  cosb  = (float*)(ws + 41943040);
  float*  sinb  = (float*)(ws + 42205184);
  bf16_t* Ob    = (bf16_t*)(ws + 42467328);       // ..50,855,936
  bf16_t* Kp    = (bf16_t*)(ws + 52428800);       // 8,388,608 B
  bf16_t* Po    = (bf16_t*)(ws + 60817408);       // 6,291,456 B
  float*  Plp   = (float*)(ws + 67108864);        // 196,608 B

  prep_all<<<4352, 256, 0, stream>>>(hid, wqkv, wo, hidb, wqkvb, wob, cosb, sinb);
  gemm_qkv<<<dim3(24, 32), 256, 0, stream>>>(hidb, wqkvb, qkvb, Kp, cosb, sinb);
  attn_fwd<<<1408, 128, 0, stream>>>(qkvb, Kp, Ob, Po, Plp);
  attn_combine<<<384, 64, 0, stream>>>(Po, Plp, Ob);
  gemm_nt_f32<<<dim3(8, 32), 256, 0, stream>>>(Ob, wob, out, 4096, 1024, 1024);
}

// Round 18
// 114.181 us; speedup vs baseline: 1.0170x; 1.0170x over previous
//
#include <hip/hip_runtime.h>
#include <hip/hip_bf16.h>
#include <math.h>

typedef __bf16 bf16_t;
typedef __attribute__((ext_vector_type(8))) __bf16 bf16x8;
typedef __attribute__((ext_vector_type(4))) float f32x4;
typedef __attribute__((ext_vector_type(16))) float f32x16;
typedef __attribute__((ext_vector_type(4))) unsigned u32x4;

#define AS1(p) ((__attribute__((address_space(1))) void*)(p))
#define AS3(p) ((__attribute__((address_space(3))) void*)(p))

__device__ inline unsigned pkbf(float a, float b) {
  bf16_t x = (bf16_t)a, y = (bf16_t)b;
  return (unsigned)__builtin_bit_cast(unsigned short, x) |
         ((unsigned)__builtin_bit_cast(unsigned short, y) << 16);
}
__device__ inline f32x16 zero16() {
  f32x16 z;
#pragma unroll
  for (int r = 0; r < 16; ++r) z[r] = 0.f;
  return z;
}

__device__ inline void cvt8(const float* __restrict__ in, bf16_t* __restrict__ out, int i) {
  const float4* p = (const float4*)in;
  float4 a = p[2 * i], b = p[2 * i + 1];
  bf16x8 o;
  o[0] = (bf16_t)a.x; o[1] = (bf16_t)a.y; o[2] = (bf16_t)a.z; o[3] = (bf16_t)a.w;
  o[4] = (bf16_t)b.x; o[5] = (bf16_t)b.y; o[6] = (bf16_t)b.z; o[7] = (bf16_t)b.w;
  ((bf16x8*)out)[i] = o;
}

// ---------------- fused prep: 3x f32->bf16 cvt + RoPE tables ----------------
__global__ __launch_bounds__(256)
void prep_all(const float* __restrict__ hid, const float* __restrict__ wqkv,
              const float* __restrict__ wo, bf16_t* __restrict__ hidb,
              bf16_t* __restrict__ wqkvb, bf16_t* __restrict__ wob,
              float* __restrict__ cosb, float* __restrict__ sinb) {
  const int bid = blockIdx.x, tid = threadIdx.x;
  if (bid < 2048) {
    cvt8(hid, hidb, bid * 256 + tid);
  } else if (bid < 3584) {
    cvt8(wqkv, wqkvb, (bid - 2048) * 256 + tid);
  } else if (bid < 4096) {
    cvt8(wo, wob, (bid - 3584) * 256 + tid);
  } else {
    int t = (bid - 4096) * 256 + tid;  // 65536 entries: [2048][32]
    int s = t >> 5, i = t & 31;
    float inv = powf(10000.0f, -(float)i / 32.0f);
    float sv, cv;
    sincosf((float)s * inv, &sv, &cv);
    cosb[t] = cv;
    sinb[t] = sv;
  }
}

// ---- BK=32 triple-buffer staging with T2 chunk swizzle (rule #21):
// linear LDS dest, source column pre-swizzled by chunk ^= (row>>1)&3.
#define GSTAGE32(KT, BUF)                                                                  \
  do {                                                                                     \
    const int k0_ = (KT) << 5;                                                             \
    const int ar_ = tid >> 2;                                                              \
    const int sw_ = (ar_ >> 1) & 3;                                                        \
    const int ac_ = (((tid & 3) ^ sw_) * 8);                                               \
    const int dc_ = (tid & 3) * 8;                                                         \
    __builtin_amdgcn_global_load_lds(AS1(A + (size_t)(m0 + ar_) * K + k0_ + ac_),          \
                                     AS3(&lA[BUF][ar_ * 32 + dc_]), 16, 0, 0);             \
    __builtin_amdgcn_global_load_lds(AS1(A + (size_t)(m0 + 64 + ar_) * K + k0_ + ac_),     \
                                     AS3(&lA[BUF][(64 + ar_) * 32 + dc_]), 16, 0, 0);      \
    __builtin_amdgcn_global_load_lds(AS1(B + (size_t)(n0 + ar_) * K + k0_ + ac_),          \
                                     AS3(&lB[BUF][ar_ * 32 + dc_]), 16, 0, 0);             \
    __builtin_amdgcn_global_load_lds(AS1(B + (size_t)(n0 + 64 + ar_) * K + k0_ + ac_),     \
                                     AS3(&lB[BUF][(64 + ar_) * 32 + dc_]), 16, 0, 0);      \
  } while (0)

// ---------------- QKV GEMM, BK=32 triple-buffer + fused rope/pack epilogue ----
__global__ __launch_bounds__(256, 3)
void gemm_qkv(const bf16_t* __restrict__ A, const bf16_t* __restrict__ B,
              bf16_t* __restrict__ qkv, bf16_t* __restrict__ Kp,
              const float* __restrict__ cosb, const float* __restrict__ sinb) {
  __shared__ __align__(16) bf16_t lA[3][128 * 32];
  __shared__ __align__(16) bf16_t lB[3][128 * 32];
  const int K = 1024;
  const int tid = threadIdx.x;
  const int wid = tid >> 6, lane = tid & 63;
  const int lr = lane & 15, lg = lane >> 4;
  const int swr = (lr >> 1) & 3;             // read-side swizzle (row-uniform in i)
  const int nwg = gridDim.x * gridDim.y;
  int lin = blockIdx.y * gridDim.x + blockIdx.x;
  lin = (lin & 7) * (nwg >> 3) + (lin >> 3);
  const int m0 = (lin / gridDim.x) * 128, n0 = (lin % gridDim.x) * 128;
  const int wm = (wid >> 1) * 64, wn = (wid & 1) * 64;
  f32x4 acc[4][4];
#pragma unroll
  for (int i = 0; i < 4; ++i)
#pragma unroll
    for (int j = 0; j < 4; ++j) acc[i][j] = f32x4{0.f, 0.f, 0.f, 0.f};

  const int nk = 32;
  GSTAGE32(0, 0);
  GSTAGE32(1, 1);
  int cbuf = 0;
  for (int kt = 0; kt < nk; ++kt) {
    if (kt + 2 < nk) {
      const int sb = cbuf == 0 ? 2 : cbuf - 1;  // (kt+2)%3
      GSTAGE32(kt + 2, sb);
      asm volatile("s_waitcnt vmcnt(8)" ::: "memory");   // tile kt landed; kt+1,kt+2 fly
    } else if (kt + 1 < nk) {
      asm volatile("s_waitcnt vmcnt(4)" ::: "memory");
    } else {
      asm volatile("s_waitcnt vmcnt(0)" ::: "memory");
    }
    __builtin_amdgcn_s_barrier();
    {
      bf16x8 af[4], bfr[4];
#pragma unroll
      for (int i = 0; i < 4; ++i) {
        af[i]  = *(const bf16x8*)&lA[cbuf][(wm + i * 16 + lr) * 32 + ((lg ^ swr) * 8)];
        bfr[i] = *(const bf16x8*)&lB[cbuf][(wn + i * 16 + lr) * 32 + ((lg ^ swr) * 8)];
      }
#pragma unroll
      for (int i = 0; i < 4; ++i)
#pragma unroll
        for (int j = 0; j < 4; ++j)
          acc[i][j] = __builtin_amdgcn_mfma_f32_16x16x32_bf16(af[i], bfr[j], acc[i][j], 0, 0, 0);
    }
    __builtin_amdgcn_s_barrier();  // all waves done with cbuf before restage
    cbuf = cbuf == 2 ? 0 : cbuf + 1;
  }
  // -------- fused epilogue --------
  const int sec = n0 >> 10;                  // 0=Q 1=K 2=V (uniform per block)
  const int hcol = ((n0 + wn) & 1023) >> 6;  // head index (uniform per wave)
  if (sec == 2) {
    // V^T: lane owns d-col (j*16+lr); 4 consecutive kv rows per acc reg.
#pragma unroll
    for (int i = 0; i < 4; ++i) {
      int token0 = m0 + wm + i * 16 + lg * 4;  // r = 0 row
      int bb = token0 >> 11;
      int t = (token0 & 2047) >> 6;
      int kv0 = token0 & 63;  // multiple of 4
      bf16_t* vd = qkv + ((size_t)(bb * 2048 + t * 64)) * 3072 + 2048 + hcol * 64;
#pragma unroll
      for (int j = 0; j < 4; ++j) {
        int d = j * 16 + lr;
        uint2 w;
        w.x = pkbf(acc[i][j][0], acc[i][j][1]);
        w.y = pkbf(acc[i][j][2], acc[i][j][3]);
        *(uint2*)(vd + (size_t)d * 3072 + (((kv0 >> 3) ^ (d & 7)) * 8) + (kv0 & 7)) = w;
      }
    }
  } else {
    const float SC = sec ? 1.0f : 0.125f * 1.4426950408889634f;  // Q: 1/8*log2e
#pragma unroll
    for (int i = 0; i < 4; ++i)
#pragma unroll
      for (int r = 0; r < 4; ++r) {
        int token = m0 + wm + i * 16 + lg * 4 + r;
        int s = token & 2047;
#pragma unroll
        for (int j = 0; j < 2; ++j) {
          int f = j * 16 + lr;  // rope pair (f, f+32) = acc regs j and j+2
          float cv = cosb[s * 32 + f], sv = sinb[s * 32 + f];
          float x1 = acc[i][j][r], x2 = acc[i][j + 2][r];
          float y1 = (x1 * cv - x2 * sv) * SC;
          float y2 = (x2 * cv + x1 * sv) * SC;
          if (sec == 0) {
            bf16_t* qd = qkv + (size_t)token * 3072 + hcol * 64;
            qd[f] = (bf16_t)y1;
            qd[f + 32] = (bf16_t)y2;
          } else {
            int bb = token >> 11, t = (token & 2047) >> 6, rk = token & 63;
            bf16_t* kd = Kp + ((size_t)((bb * 16 + hcol) * 32 + t)) * 4096 + rk * 64;
            int c1 = f >> 3;  // chunk of d=f; d+32 -> c1+4
            kd[((c1 ^ (rk & 7)) * 8) + (lr & 7)] = (bf16_t)y1;
            kd[(((c1 + 4) ^ (rk & 7)) * 8) + (lr & 7)] = (bf16_t)y2;
          }
        }
      }
  }
}

// ---------------- out-proj GEMM (f32 out), BK=32 triple-buffer ----------------
__global__ __launch_bounds__(256, 3)
void gemm_nt_f32(const bf16_t* __restrict__ A, const bf16_t* __restrict__ B,
                 float* __restrict__ C, int M, int N, int K) {
  __shared__ __align__(16) bf16_t lA[3][128 * 32];
  __shared__ __align__(16) bf16_t lB[3][128 * 32];
  const int tid = threadIdx.x;
  const int wid = tid >> 6, lane = tid & 63;
  const int lr = lane & 15, lg = lane >> 4;
  const int swr = (lr >> 1) & 3;
  const int nwg = gridDim.x * gridDim.y;
  int lin = blockIdx.y * gridDim.x + blockIdx.x;
  lin = (lin & 7) * (nwg >> 3) + (lin >> 3);
  const int m0 = (lin / gridDim.x) * 128, n0 = (lin % gridDim.x) * 128;
  const int wm = (wid >> 1) * 64, wn = (wid & 1) * 64;
  f32x4 acc[4][4];
#pragma unroll
  for (int i = 0; i < 4; ++i)
#pragma unroll
    for (int j = 0; j < 4; ++j) acc[i][j] = f32x4{0.f, 0.f, 0.f, 0.f};

  const int nk = K >> 5;
  GSTAGE32(0, 0);
  GSTAGE32(1, 1);
  int cbuf = 0;
  for (int kt = 0; kt < nk; ++kt) {
    if (kt + 2 < nk) {
      const int sb = cbuf == 0 ? 2 : cbuf - 1;
      GSTAGE32(kt + 2, sb);
      asm volatile("s_waitcnt vmcnt(8)" ::: "memory");
    } else if (kt + 1 < nk) {
      asm volatile("s_waitcnt vmcnt(4)" ::: "memory");
    } else {
      asm volatile("s_waitcnt vmcnt(0)" ::: "memory");
    }
    __builtin_amdgcn_s_barrier();
    {
      bf16x8 af[4], bfr[4];
#pragma unroll
      for (int i = 0; i < 4; ++i) {
        af[i]  = *(const bf16x8*)&lA[cbuf][(wm + i * 16 + lr) * 32 + ((lg ^ swr) * 8)];
        bfr[i] = *(const bf16x8*)&lB[cbuf][(wn + i * 16 + lr) * 32 + ((lg ^ swr) * 8)];
      }
#pragma unroll
      for (int i = 0; i < 4; ++i)
#pragma unroll
        for (int j = 0; j < 4; ++j)
          acc[i][j] = __builtin_amdgcn_mfma_f32_16x16x32_bf16(af[i], bfr[j], acc[i][j], 0, 0, 0);
    }
    __builtin_amdgcn_s_barrier();
    cbuf = cbuf == 2 ? 0 : cbuf + 1;
  }
#pragma unroll
  for (int i = 0; i < 4; ++i)
#pragma unroll
    for (int j = 0; j < 4; ++j)
#pragma unroll
      for (int r = 0; r < 4; ++r) {
        int row = m0 + wm + i * 16 + lg * 4 + r;
        int col = n0 + wn + j * 16 + lr;
        C[(size_t)row * N + col] = acc[i][j][r];
      }
}

// ---------------- flash attention (round-12 best-measured): split-kv halves ----
__device__ const unsigned char ROLE_LUT[44] = {
    19, 18, 17, 16,
    15, 95, 159, 158,
    14, 94, 93, 157,
    13, 92, 156, 91, 155, 154,
    12, 90, 89, 153, 152,
    11, 88, 87, 151, 150,
    10, 86, 85, 149, 148,
    9, 84,
    8, 7, 6, 5, 4, 3, 2, 1, 0};

__global__ __launch_bounds__(128, 2)
void attn_fwd(const bf16_t* __restrict__ qkv, const bf16_t* __restrict__ Kp,
              bf16_t* __restrict__ O, bf16_t* __restrict__ Po, float* __restrict__ Plp) {
  __shared__ __align__(16) bf16_t Ksh[2][4096];
  __shared__ __align__(16) bf16_t Vsh[2][4096];
  const int tid = threadIdx.x, wid = tid >> 6, lane = tid & 63;
  const int ln = lane & 31, h = lane >> 5;
  const int lin = blockIdx.x;
  const int e = ROLE_LUT[lin >> 5];           // role, longest chains at low lin
  const int bh = lin & 31;                    // same-bh blocks share XCD (lin%8)
  const int c = e & 31, kind = e >> 6;
  const int b = bh >> 4, hd = bh & 15;
  const int t0 = (kind == 2) ? ((c + 1) >> 1) : 0;
  const int t1 = (kind == 1) ? ((c + 1) >> 1) : c + 1;
  const int qw = c * 64 + wid * 32;

  const bf16_t* Qrow = qkv + ((size_t)(b * 2048 + qw + ln)) * 3072 + hd * 64;
  bf16x8 qf[4];
#pragma unroll
  for (int t = 0; t < 4; ++t) qf[t] = *(const bf16x8*)(Qrow + t * 16 + h * 8);

  f32x16 o0 = zero16(), o1 = zero16();
  float lp = 0.f;

  const bf16_t* Kbase = Kp + ((size_t)bh * 32) * 4096 + tid * 8;
  const bf16_t* Vbase = qkv + ((size_t)(b * 2048 + (tid >> 3))) * 3072 + 2048 + hd * 64 + (tid & 7) * 8;

#define STAGE(T, BUF)                                                                     \
  do {                                                                                    \
    const bf16_t* ks = Kbase + (size_t)(T) * 4096;                                        \
    __builtin_amdgcn_global_load_lds(AS1(ks),        AS3(&Ksh[BUF][tid * 8]), 16, 0, 0);  \
    __builtin_amdgcn_global_load_lds(AS1(ks + 1024), AS3(&Ksh[BUF][1024 + tid * 8]), 16, 0, 0); \
    __builtin_amdgcn_global_load_lds(AS1(ks + 2048), AS3(&Ksh[BUF][2048 + tid * 8]), 16, 0, 0); \
    __builtin_amdgcn_global_load_lds(AS1(ks + 3072), AS3(&Ksh[BUF][3072 + tid * 8]), 16, 0, 0); \
    const bf16_t* vs = Vbase + (size_t)(T) * 64 * 3072;                                   \
    __builtin_amdgcn_global_load_lds(AS1(vs),             AS3(&Vsh[BUF][tid * 8]), 16, 0, 0);        \
    __builtin_amdgcn_global_load_lds(AS1(vs + 16 * 3072), AS3(&Vsh[BUF][1024 + tid * 8]), 16, 0, 0); \
    __builtin_amdgcn_global_load_lds(AS1(vs + 32 * 3072), AS3(&Vsh[BUF][2048 + tid * 8]), 16, 0, 0); \
    __builtin_amdgcn_global_load_lds(AS1(vs + 48 * 3072), AS3(&Vsh[BUF][3072 + tid * 8]), 16, 0, 0); \
  } while (0)

  STAGE(t0, t0 & 1);
  for (int t = t0; t < t1; ++t) {
    asm volatile("s_waitcnt vmcnt(0)" ::: "memory");  // STAGE(t) done
    __builtin_amdgcn_s_barrier();                     // all waves staged; prev buf free
    if (t + 1 < t1) STAGE(t + 1, (t + 1) & 1);        // flies under this item's compute
    const bf16_t* K = &Ksh[t & 1][0];
    const bf16_t* V = &Vsh[t & 1][0];
    f32x16 s0 = zero16(), s1 = zero16();
    __builtin_amdgcn_s_setprio(1);
#pragma unroll
    for (int u = 0; u < 4; ++u) {
      const int ch = 2 * u + h;
      bf16x8 k0 = *(const bf16x8*)&K[ln * 64 + ((ch ^ (ln & 7)) * 8)];
      bf16x8 k1 = *(const bf16x8*)&K[(32 + ln) * 64 + ((ch ^ (ln & 7)) * 8)];
      s0 = __builtin_amdgcn_mfma_f32_32x32x16_bf16(k0, qf[u], s0, 0, 0, 0);
      s1 = __builtin_amdgcn_mfma_f32_32x32x16_bf16(k1, qf[u], s1, 0, 0, 0);
    }
    __builtin_amdgcn_s_setprio(0);
    if (t == c) {  // diagonal tile
      const int qg = qw + ln, k0g = t * 64;
#pragma unroll
      for (int r = 0; r < 16; ++r) {
        int kv = k0g + (r & 3) + 8 * (r >> 2) + 4 * h;
        if (kv > qg) s0[r] = -3e38f;
        if (kv + 32 > qg) s1[r] = -3e38f;
      }
    }
#pragma unroll
    for (int r = 0; r < 16; ++r) {
      float p0 = __builtin_amdgcn_exp2f(s0[r]); lp += p0; s0[r] = p0;
      float p1 = __builtin_amdgcn_exp2f(s1[r]); lp += p1; s1[r] = p1;
    }
    __builtin_amdgcn_s_setprio(1);
#pragma unroll
    for (int u = 0; u < 4; ++u) {
      const int w = u & 1;
      f32x16 sv = (u >> 1) ? s1 : s0;
      unsigned x  = pkbf(sv[8 * w + 0], sv[8 * w + 1]);
      unsigned x2 = pkbf(sv[8 * w + 2], sv[8 * w + 3]);
      unsigned y  = pkbf(sv[8 * w + 4], sv[8 * w + 5]);
      unsigned y2 = pkbf(sv[8 * w + 6], sv[8 * w + 7]);
      asm volatile("v_permlane32_swap_b32 %0, %1" : "+v"(x), "+v"(y));
      asm volatile("v_permlane32_swap_b32 %0, %1" : "+v"(x2), "+v"(y2));
      u32x4 pw; pw[0] = x; pw[1] = x2; pw[2] = y; pw[3] = y2;
      bf16x8 pf = __builtin_bit_cast(bf16x8, pw);
      const int ch = 2 * u + h;
      bf16x8 v0 = *(const bf16x8*)&V[ln * 64 + ((ch ^ (ln & 7)) * 8)];
      bf16x8 v1 = *(const bf16x8*)&V[(32 + ln) * 64 + ((ch ^ (ln & 7)) * 8)];
      o0 = __builtin_amdgcn_mfma_f32_32x32x16_bf16(v0, pf, o0, 0, 0, 0);
      o1 = __builtin_amdgcn_mfma_f32_32x32x16_bf16(v1, pf, o1, 0, 0, 0);
    }
    __builtin_amdgcn_s_setprio(0);
  }
#undef STAGE
  float lpf = lp + __shfl_xor(lp, 32, 64);
  if (kind == 0) {
    float inv = 1.0f / lpf;
    bf16_t* Oaddr = O + ((size_t)(b * 2048 + qw + ln)) * 1024 + hd * 64;
#pragma unroll
    for (int D = 0; D < 2; ++D) {
      f32x16 ov = D ? o1 : o0;
#pragma unroll
      for (int Q = 0; Q < 4; ++Q) {
        uint2 w;
        w.x = pkbf(ov[4 * Q + 0] * inv, ov[4 * Q + 1] * inv);
        w.y = pkbf(ov[4 * Q + 2] * inv, ov[4 * Q + 3] * inv);
        *(uint2*)(Oaddr + D * 32 + Q * 8 + 4 * h) = w;
      }
    }
  } else {
    const int slot = (bh * 12 + (c - 20)) * 2 + (kind - 1);
    const int qi = wid * 32 + ln;
    if (h == 0) Plp[slot * 64 + qi] = lpf;
    bf16_t* Paddr = Po + ((size_t)(slot * 64 + qi)) * 64;
#pragma unroll
    for (int D = 0; D < 2; ++D) {
      f32x16 ov = D ? o1 : o0;
#pragma unroll
      for (int Q = 0; Q < 4; ++Q) {
        uint2 w;
        w.x = pkbf(ov[4 * Q + 0], ov[4 * Q + 1]);
        w.y = pkbf(ov[4 * Q + 2], ov[4 * Q + 3]);
        *(uint2*)(Paddr + D * 32 + Q * 8 + 4 * h) = w;
      }
    }
  }
}

// ---------------- combine split-kv partials: O = (oA+oB)/(lpA+lpB) ----
__global__ __launch_bounds__(64)
void attn_combine(const bf16_t* __restrict__ Po, const float* __restrict__ Plp,
                  bf16_t* __restrict__ O) {
  const int blk = blockIdx.x;  // 384 = bh*12 + sc
  const int bh = blk / 12, sc = blk % 12;
  const int b = bh >> 4, hd = bh & 15;
  const int c = 20 + sc;
  const int q = threadIdx.x;  // 64 q-rows
  const int slotA = (bh * 12 + sc) * 2, slotB = slotA + 1;
  float inv = 1.0f / (Plp[slotA * 64 + q] + Plp[slotB * 64 + q]);
  const bf16x8* pa = (const bf16x8*)(Po + ((size_t)(slotA * 64 + q)) * 64);
  const bf16x8* pb = (const bf16x8*)(Po + ((size_t)(slotB * 64 + q)) * 64);
  bf16_t* oaddr = O + ((size_t)(b * 2048 + c * 64 + q)) * 1024 + hd * 64;
#pragma unroll
  for (int j = 0; j < 8; ++j) {
    bf16x8 a = pa[j], v = pb[j];
    bf16x8 w;
#pragma unroll
    for (int k = 0; k < 8; ++k) w[k] = (bf16_t)(((float)a[k] + (float)v[k]) * inv);
    ((bf16x8*)oaddr)[j] = w;
  }
}

extern "C" void kernel_launch(void* const* d_in, const int* in_sizes, int n_in,
                              void* d_out, int out_size, void* d_ws, size_t ws_size,
                              hipStream_t stream) {
  const float* hid  = (const float*)d_in[0];   // [4096,1024]
  const float* wqkv = (const float*)d_in[1];   // [3072,1024]
  const float* wo   = (const float*)d_in[2];   // [1024,1024]
  float* out = (float*)d_out;                  // [4096,1024] f32
  char* ws = (char*)d_ws;
  bf16_t* hidb  = (bf16_t*)(ws);                  // 0..8M
  bf16_t* wqkvb = (bf16_t*)(ws + 8388608);        // 8M..14M
  bf16_t* wob   = (bf16_t*)(ws + 14680064);       // 14M..16M
  bf16_t* qkvb  = (bf16_t*)(ws + 16777216);       // 16M..40M (Q | dead | V^T)
  float*  cosb  = (float*)(ws + 41943040);
  float*  sinb  = (float*)(ws + 42205184);
  bf16_t* Ob    = (bf16_t*)(ws + 42467328);       // ..50,855,936
  bf16_t* Kp    = (bf16_t*)(ws + 52428800);       // 8,388,608 B
  bf16_t* Po    = (bf16_t*)(ws + 60817408);       // 6,291,456 B
  float*  Plp   = (float*)(ws + 67108864);        // 196,608 B

  prep_all<<<4352, 256, 0, stream>>>(hid, wqkv, wo, hidb, wqkvb, wob, cosb, sinb);
  gemm_qkv<<<dim3(24, 32), 256, 0, stream>>>(hidb, wqkvb, qkvb, Kp, cosb, sinb);
  attn_fwd<<<1408, 128, 0, stream>>>(qkvb, Kp, Ob, Po, Plp);
  attn_combine<<<384, 64, 0, stream>>>(Po, Plp, Ob);
  gemm_nt_f32<<<dim3(8, 32), 256, 0, stream>>>(Ob, wob, out, 4096, 1024, 1024);
}